// Round 2
// 2534.713 us; speedup vs baseline: 2.0559x; 2.0559x over previous
//
#include <hip/hip_runtime.h>

#define N_NODES 50000
#define N_EDGES 800000
#define DIM 96

// GEMM tile geometry: 256 threads, 64-row x 96-col output tile.
// thread (tx = t&7, ty = t>>3) owns rows {2ty, 2ty+1} x cols [12tx, 12tx+12).
#define BM 64
#define BK 48
#define APAD 52   // As row stride (floats). Read stride 2*52 % 32 = 8 -> 2-way (free).
#define HPAD 100  // Hs row stride. 2*100 % 32 = 8 -> 2-way (free). Rows 16B-aligned.

#define FMA4(C, A, W)        \
  C.x = fmaf(A, W.x, C.x);   \
  C.y = fmaf(A, W.y, C.y);   \
  C.z = fmaf(A, W.z, C.z);   \
  C.w = fmaf(A, W.w, C.w)

#define BIAS_RELU4(C, B)          \
  C.x = fmaxf(C.x + B.x, 0.0f);   \
  C.y = fmaxf(C.y + B.y, 0.0f);   \
  C.z = fmaxf(C.z + B.z, 0.0f);   \
  C.w = fmaxf(C.w + B.w, 0.0f)

#define BIAS4(C, B) \
  C.x += B.x;       \
  C.y += B.y;       \
  C.z += B.z;       \
  C.w += B.w

// ---------------------------------------------------------------------------
// Kernel 1: scatter-add edge_attr rows into agg[dst].
// ---------------------------------------------------------------------------
__global__ __launch_bounds__(256) void scatter_kernel(
    const float* __restrict__ edge_attr, const int* __restrict__ ei,
    float* __restrict__ agg) {
  int tid = blockIdx.x * 256 + threadIdx.x;
  if (tid >= N_EDGES * 24) return;
  int e = tid / 24;
  int c = tid - e * 24;
  int d = ei[N_EDGES + e];
  const float4 v =
      *reinterpret_cast<const float4*>(edge_attr + (size_t)e * DIM + c * 4);
  float* p = agg + (size_t)d * DIM + c * 4;
  atomicAdd(p + 0, v.x);
  atomicAdd(p + 1, v.y);
  atomicAdd(p + 2, v.z);
  atomicAdd(p + 3, v.w);
}

// ---------------------------------------------------------------------------
// Kernel 2: copy edge_index to output as floats.
// ---------------------------------------------------------------------------
__global__ __launch_bounds__(256) void copy_ei_kernel(
    const int* __restrict__ ei, float* __restrict__ out) {
  int tid = blockIdx.x * 256 + threadIdx.x;
  if (tid < 2 * N_EDGES) out[tid] = (float)ei[tid];
}

// ---------------------------------------------------------------------------
// Kernel 3: node MLP as register-tiled GEMM. K=192 (x || agg), fused 2 layers.
// ---------------------------------------------------------------------------
__global__ __launch_bounds__(256, 2) void node_mlp_kernel(
    const float* __restrict__ x, const float* __restrict__ agg,
    const float* __restrict__ W1, const float* __restrict__ b1,
    const float* __restrict__ W2, const float* __restrict__ b2,
    float* __restrict__ out) {
  __shared__ float As[BM * APAD];   // 13.3 KB
  __shared__ float Ws[BK * DIM];    // 18.0 KB
  __shared__ float Hs[BM * HPAD];   // 25.6 KB

  const int t = threadIdx.x;
  const int tx = t & 7;
  const int ty = t >> 3;
  const int r0 = ty * 2;
  const int n0 = blockIdx.x * BM;
  const int cbase = tx * 12;

  float4 c00 = make_float4(0.f, 0.f, 0.f, 0.f);
  float4 c01 = c00, c02 = c00, c10 = c00, c11 = c00, c12 = c00;

  // ----- layer 1: acc = A[64 x 192] @ W1[192 x 96], K-chunks of 48 -----
  for (int ch = 0; ch < 4; ++ch) {
    const int k0 = ch * BK;
    __syncthreads();
    // stage A chunk: 64 rows x 48 cols = 768 float4s, 3 per thread
#pragma unroll
    for (int m = 0; m < 3; ++m) {
      const int idx = m * 256 + t;
      const int row = idx / 12;
      const int c4 = (idx - row * 12) * 4;
      const int col = k0 + c4;
      int n = n0 + row;
      n = (n < N_NODES) ? n : 0;  // clamp; garbage rows never stored
      const float* src = (col < DIM) ? x + (size_t)n * DIM + col
                                     : agg + (size_t)n * DIM + (col - DIM);
      *reinterpret_cast<float4*>(&As[row * APAD + c4]) =
          *reinterpret_cast<const float4*>(src);
    }
    // stage W1 chunk: 48 x 96 = 1152 float4s
#pragma unroll
    for (int m = 0; m < 5; ++m) {
      const int idx = m * 256 + t;
      if (idx < (BK * DIM) / 4) {
        const int wr = idx / 24;
        const int wc = (idx - wr * 24) * 4;
        *reinterpret_cast<float4*>(&Ws[wr * DIM + wc]) =
            *reinterpret_cast<const float4*>(W1 + (size_t)(k0 + wr) * DIM + wc);
      }
    }
    __syncthreads();
#pragma unroll 4
    for (int k = 0; k < BK; ++k) {
      const float a0 = As[(r0 + 0) * APAD + k];
      const float a1 = As[(r0 + 1) * APAD + k];
      const float4 w0 =
          *reinterpret_cast<const float4*>(&Ws[k * DIM + cbase + 0]);
      const float4 w1 =
          *reinterpret_cast<const float4*>(&Ws[k * DIM + cbase + 4]);
      const float4 w2 =
          *reinterpret_cast<const float4*>(&Ws[k * DIM + cbase + 8]);
      FMA4(c00, a0, w0);
      FMA4(c01, a0, w1);
      FMA4(c02, a0, w2);
      FMA4(c10, a1, w0);
      FMA4(c11, a1, w1);
      FMA4(c12, a1, w2);
    }
  }

  // bias + relu -> Hs
  {
    const float4 bb0 = *reinterpret_cast<const float4*>(b1 + cbase + 0);
    const float4 bb1 = *reinterpret_cast<const float4*>(b1 + cbase + 4);
    const float4 bb2 = *reinterpret_cast<const float4*>(b1 + cbase + 8);
    BIAS_RELU4(c00, bb0);
    BIAS_RELU4(c01, bb1);
    BIAS_RELU4(c02, bb2);
    BIAS_RELU4(c10, bb0);
    BIAS_RELU4(c11, bb1);
    BIAS_RELU4(c12, bb2);
    *reinterpret_cast<float4*>(&Hs[(r0 + 0) * HPAD + cbase + 0]) = c00;
    *reinterpret_cast<float4*>(&Hs[(r0 + 0) * HPAD + cbase + 4]) = c01;
    *reinterpret_cast<float4*>(&Hs[(r0 + 0) * HPAD + cbase + 8]) = c02;
    *reinterpret_cast<float4*>(&Hs[(r0 + 1) * HPAD + cbase + 0]) = c10;
    *reinterpret_cast<float4*>(&Hs[(r0 + 1) * HPAD + cbase + 4]) = c11;
    *reinterpret_cast<float4*>(&Hs[(r0 + 1) * HPAD + cbase + 8]) = c12;
  }

  // ----- layer 2: out = relu_h[64 x 96] @ W2[96 x 96] -----
  c00 = make_float4(0.f, 0.f, 0.f, 0.f);
  c01 = c00;
  c02 = c00;
  c10 = c00;
  c11 = c00;
  c12 = c00;
  for (int ch = 0; ch < 2; ++ch) {
    const int k0 = ch * BK;
    __syncthreads();  // Hs writes visible; previous Ws readers done
#pragma unroll
    for (int m = 0; m < 5; ++m) {
      const int idx = m * 256 + t;
      if (idx < (BK * DIM) / 4) {
        const int wr = idx / 24;
        const int wc = (idx - wr * 24) * 4;
        *reinterpret_cast<float4*>(&Ws[wr * DIM + wc]) =
            *reinterpret_cast<const float4*>(W2 + (size_t)(k0 + wr) * DIM + wc);
      }
    }
    __syncthreads();
#pragma unroll 4
    for (int k = 0; k < BK; ++k) {
      const float a0 = Hs[(r0 + 0) * HPAD + k0 + k];
      const float a1 = Hs[(r0 + 1) * HPAD + k0 + k];
      const float4 w0 =
          *reinterpret_cast<const float4*>(&Ws[k * DIM + cbase + 0]);
      const float4 w1 =
          *reinterpret_cast<const float4*>(&Ws[k * DIM + cbase + 4]);
      const float4 w2 =
          *reinterpret_cast<const float4*>(&Ws[k * DIM + cbase + 8]);
      FMA4(c00, a0, w0);
      FMA4(c01, a0, w1);
      FMA4(c02, a0, w2);
      FMA4(c10, a1, w0);
      FMA4(c11, a1, w1);
      FMA4(c12, a1, w2);
    }
  }

  {
    const float4 bb0 = *reinterpret_cast<const float4*>(b2 + cbase + 0);
    const float4 bb1 = *reinterpret_cast<const float4*>(b2 + cbase + 4);
    const float4 bb2 = *reinterpret_cast<const float4*>(b2 + cbase + 8);
    BIAS4(c00, bb0);
    BIAS4(c01, bb1);
    BIAS4(c02, bb2);
    BIAS4(c10, bb0);
    BIAS4(c11, bb1);
    BIAS4(c12, bb2);
    const int n_r0 = n0 + r0;
    if (n_r0 < N_NODES) {
      float* o = out + (size_t)n_r0 * DIM + cbase;
      *reinterpret_cast<float4*>(o + 0) = c00;
      *reinterpret_cast<float4*>(o + 4) = c01;
      *reinterpret_cast<float4*>(o + 8) = c02;
    }
    if (n_r0 + 1 < N_NODES) {
      float* o = out + (size_t)(n_r0 + 1) * DIM + cbase;
      *reinterpret_cast<float4*>(o + 0) = c10;
      *reinterpret_cast<float4*>(o + 4) = c11;
      *reinterpret_cast<float4*>(o + 8) = c12;
    }
  }
}

// ---------------------------------------------------------------------------
// Kernel 4: edge MLP as register-tiled GEMM. K=288 (x[src] || x[dst] || ea).
// N_EDGES % 64 == 0, so no row guards.
// ---------------------------------------------------------------------------
__global__ __launch_bounds__(256, 2) void edge_mlp_kernel(
    const float* __restrict__ x, const int* __restrict__ ei,
    const float* __restrict__ ea, const float* __restrict__ W1,
    const float* __restrict__ b1, const float* __restrict__ W2,
    const float* __restrict__ b2, float* __restrict__ out) {
  __shared__ int s_src[BM];
  __shared__ int s_dst[BM];
  __shared__ float As[BM * APAD];
  __shared__ float Ws[BK * DIM];
  __shared__ float Hs[BM * HPAD];

  const int t = threadIdx.x;
  const int tx = t & 7;
  const int ty = t >> 3;
  const int r0 = ty * 2;
  const int e0 = blockIdx.x * BM;
  const int cbase = tx * 12;

  if (t < BM) {
    s_src[t] = ei[e0 + t];
    s_dst[t] = ei[N_EDGES + e0 + t];
  }

  float4 c00 = make_float4(0.f, 0.f, 0.f, 0.f);
  float4 c01 = c00, c02 = c00, c10 = c00, c11 = c00, c12 = c00;

  // ----- layer 1: K = 288, 6 chunks of 48. Each chunk lies entirely within
  // one concat segment (chunks 0-1: x[src], 2-3: x[dst], 4-5: ea). -----
  for (int ch = 0; ch < 6; ++ch) {
    const int k0 = ch * BK;
    __syncthreads();  // also covers the s_src/s_dst writes on ch==0
#pragma unroll
    for (int m = 0; m < 3; ++m) {
      const int idx = m * 256 + t;
      const int row = idx / 12;
      const int c4 = (idx - row * 12) * 4;
      const int col = k0 + c4;
      const float* src;
      if (col < DIM)
        src = x + (size_t)s_src[row] * DIM + col;
      else if (col < 2 * DIM)
        src = x + (size_t)s_dst[row] * DIM + (col - DIM);
      else
        src = ea + (size_t)(e0 + row) * DIM + (col - 2 * DIM);
      *reinterpret_cast<float4*>(&As[row * APAD + c4]) =
          *reinterpret_cast<const float4*>(src);
    }
#pragma unroll
    for (int m = 0; m < 5; ++m) {
      const int idx = m * 256 + t;
      if (idx < (BK * DIM) / 4) {
        const int wr = idx / 24;
        const int wc = (idx - wr * 24) * 4;
        *reinterpret_cast<float4*>(&Ws[wr * DIM + wc]) =
            *reinterpret_cast<const float4*>(W1 + (size_t)(k0 + wr) * DIM + wc);
      }
    }
    __syncthreads();
#pragma unroll 4
    for (int k = 0; k < BK; ++k) {
      const float a0 = As[(r0 + 0) * APAD + k];
      const float a1 = As[(r0 + 1) * APAD + k];
      const float4 w0 =
          *reinterpret_cast<const float4*>(&Ws[k * DIM + cbase + 0]);
      const float4 w1 =
          *reinterpret_cast<const float4*>(&Ws[k * DIM + cbase + 4]);
      const float4 w2 =
          *reinterpret_cast<const float4*>(&Ws[k * DIM + cbase + 8]);
      FMA4(c00, a0, w0);
      FMA4(c01, a0, w1);
      FMA4(c02, a0, w2);
      FMA4(c10, a1, w0);
      FMA4(c11, a1, w1);
      FMA4(c12, a1, w2);
    }
  }

  // bias + relu -> Hs
  {
    const float4 bb0 = *reinterpret_cast<const float4*>(b1 + cbase + 0);
    const float4 bb1 = *reinterpret_cast<const float4*>(b1 + cbase + 4);
    const float4 bb2 = *reinterpret_cast<const float4*>(b1 + cbase + 8);
    BIAS_RELU4(c00, bb0);
    BIAS_RELU4(c01, bb1);
    BIAS_RELU4(c02, bb2);
    BIAS_RELU4(c10, bb0);
    BIAS_RELU4(c11, bb1);
    BIAS_RELU4(c12, bb2);
    *reinterpret_cast<float4*>(&Hs[(r0 + 0) * HPAD + cbase + 0]) = c00;
    *reinterpret_cast<float4*>(&Hs[(r0 + 0) * HPAD + cbase + 4]) = c01;
    *reinterpret_cast<float4*>(&Hs[(r0 + 0) * HPAD + cbase + 8]) = c02;
    *reinterpret_cast<float4*>(&Hs[(r0 + 1) * HPAD + cbase + 0]) = c10;
    *reinterpret_cast<float4*>(&Hs[(r0 + 1) * HPAD + cbase + 4]) = c11;
    *reinterpret_cast<float4*>(&Hs[(r0 + 1) * HPAD + cbase + 8]) = c12;
  }

  // ----- layer 2 -----
  c00 = make_float4(0.f, 0.f, 0.f, 0.f);
  c01 = c00;
  c02 = c00;
  c10 = c00;
  c11 = c00;
  c12 = c00;
  for (int ch = 0; ch < 2; ++ch) {
    const int k0 = ch * BK;
    __syncthreads();
#pragma unroll
    for (int m = 0; m < 5; ++m) {
      const int idx = m * 256 + t;
      if (idx < (BK * DIM) / 4) {
        const int wr = idx / 24;
        const int wc = (idx - wr * 24) * 4;
        *reinterpret_cast<float4*>(&Ws[wr * DIM + wc]) =
            *reinterpret_cast<const float4*>(W2 + (size_t)(k0 + wr) * DIM + wc);
      }
    }
    __syncthreads();
#pragma unroll 4
    for (int k = 0; k < BK; ++k) {
      const float a0 = Hs[(r0 + 0) * HPAD + k0 + k];
      const float a1 = Hs[(r0 + 1) * HPAD + k0 + k];
      const float4 w0 =
          *reinterpret_cast<const float4*>(&Ws[k * DIM + cbase + 0]);
      const float4 w1 =
          *reinterpret_cast<const float4*>(&Ws[k * DIM + cbase + 4]);
      const float4 w2 =
          *reinterpret_cast<const float4*>(&Ws[k * DIM + cbase + 8]);
      FMA4(c00, a0, w0);
      FMA4(c01, a0, w1);
      FMA4(c02, a0, w2);
      FMA4(c10, a1, w0);
      FMA4(c11, a1, w1);
      FMA4(c12, a1, w2);
    }
  }

  {
    const float4 bb0 = *reinterpret_cast<const float4*>(b2 + cbase + 0);
    const float4 bb1 = *reinterpret_cast<const float4*>(b2 + cbase + 4);
    const float4 bb2 = *reinterpret_cast<const float4*>(b2 + cbase + 8);
    BIAS4(c00, bb0);
    BIAS4(c01, bb1);
    BIAS4(c02, bb2);
    BIAS4(c10, bb0);
    BIAS4(c11, bb1);
    BIAS4(c12, bb2);
    float* o0 = out + (size_t)(e0 + r0) * DIM + cbase;
    float* o1 = out + (size_t)(e0 + r0 + 1) * DIM + cbase;
    *reinterpret_cast<float4*>(o0 + 0) = c00;
    *reinterpret_cast<float4*>(o0 + 4) = c01;
    *reinterpret_cast<float4*>(o0 + 8) = c02;
    *reinterpret_cast<float4*>(o1 + 0) = c10;
    *reinterpret_cast<float4*>(o1 + 4) = c11;
    *reinterpret_cast<float4*>(o1 + 8) = c12;
  }
}

// ---------------------------------------------------------------------------
extern "C" void kernel_launch(void* const* d_in, const int* in_sizes, int n_in,
                              void* d_out, int out_size, void* d_ws,
                              size_t ws_size, hipStream_t stream) {
  const float* x = (const float*)d_in[0];
  const int* ei = (const int*)d_in[1];
  const float* edge_attr = (const float*)d_in[2];
  const float* Wn1 = (const float*)d_in[3];
  const float* bn1 = (const float*)d_in[4];
  const float* Wn2 = (const float*)d_in[5];
  const float* bn2 = (const float*)d_in[6];
  const float* We1 = (const float*)d_in[7];
  const float* be1 = (const float*)d_in[8];
  const float* We2 = (const float*)d_in[9];
  const float* be2 = (const float*)d_in[10];

  float* out = (float*)d_out;
  float* agg = (float*)d_ws;  // [N_NODES, DIM] fp32 scratch = 19.2 MB

  float* out_hv = out;
  float* out_ei = out + (size_t)N_NODES * DIM;
  float* out_he = out + (size_t)N_NODES * DIM + 2 * (size_t)N_EDGES;

  // agg must be zeroed every call (ws is re-poisoned by the harness).
  hipMemsetAsync(d_ws, 0, (size_t)N_NODES * DIM * sizeof(float), stream);

  scatter_kernel<<<(N_EDGES * 24 + 255) / 256, 256, 0, stream>>>(edge_attr, ei,
                                                                 agg);
  copy_ei_kernel<<<(2 * N_EDGES + 255) / 256, 256, 0, stream>>>(ei, out_ei);
  node_mlp_kernel<<<(N_NODES + BM - 1) / BM, 256, 0, stream>>>(
      x, agg, Wn1, bn1, Wn2, bn2, out_hv);
  edge_mlp_kernel<<<N_EDGES / BM, 256, 0, stream>>>(x, ei, edge_attr, We1, be1,
                                                    We2, be2, out_he);
}

// Round 3
// 1711.027 us; speedup vs baseline: 3.0456x; 1.4814x over previous
//
#include <hip/hip_runtime.h>

#define N_NODES 50000
#define N_EDGES 800000
#define DIM 96

// GEMM tile geometry: 256 threads, 64-row x 96-col output tile.
// thread (tx = t&7, ty = t>>3) owns rows {2ty, 2ty+1} x cols [12tx, 12tx+12).
#define BM 64
#define BK 48
#define APAD 52   // As row stride (floats). Read stride 2*52 % 32 = 8 -> 2-way (free).
#define HPAD 100  // Hs row stride. 2*100 % 32 = 8 -> 2-way (free). Rows 16B-aligned.

// CSR scratch layout (int offsets) inside the out_he region, which is
// overwritten by edge_mlp_kernel at the very end of the launch sequence.
#define SC_CNT 0           // [50000) histogram / per-node degree
#define SC_OFF 50000       // [50001) exclusive prefix (CSR row offsets)
#define SC_CUR 100016      // [50000) fill cursors
#define SC_BSUM 150016     // [256)   per-block partial sums for the scan
#define SC_EIDX 150528     // [800000) edge ids sorted by destination
#define NBLK_SCAN 196      // ceil(50000/256)

#define FMA4(C, A, W)        \
  C.x = fmaf(A, W.x, C.x);   \
  C.y = fmaf(A, W.y, C.y);   \
  C.z = fmaf(A, W.z, C.z);   \
  C.w = fmaf(A, W.w, C.w)

#define BIAS_RELU4(C, B)          \
  C.x = fmaxf(C.x + B.x, 0.0f);   \
  C.y = fmaxf(C.y + B.y, 0.0f);   \
  C.z = fmaxf(C.z + B.z, 0.0f);   \
  C.w = fmaxf(C.w + B.w, 0.0f)

#define BIAS4(C, B) \
  C.x += B.x;       \
  C.y += B.y;       \
  C.z += B.z;       \
  C.w += B.w

// ---------------------------------------------------------------------------
// CSR build stage 1: per-destination histogram. 1.6M int atomics total
// (vs 76.8M fp32 atomics in the old scatter) across hist+fill.
// ---------------------------------------------------------------------------
__global__ __launch_bounds__(256) void hist_kernel(const int* __restrict__ ei,
                                                   int* __restrict__ sc) {
  int e = blockIdx.x * 256 + threadIdx.x;
  if (e < N_EDGES) atomicAdd(&sc[SC_CNT + ei[N_EDGES + e]], 1);
}

// ---------------------------------------------------------------------------
// CSR build stage 2a: per-block sums of the histogram.
// ---------------------------------------------------------------------------
__global__ __launch_bounds__(256) void scan1_kernel(int* __restrict__ sc) {
  __shared__ int s[256];
  int i = blockIdx.x * 256 + threadIdx.x;
  s[threadIdx.x] = (i < N_NODES) ? sc[SC_CNT + i] : 0;
  __syncthreads();
  for (int off = 128; off > 0; off >>= 1) {
    if (threadIdx.x < off) s[threadIdx.x] += s[threadIdx.x + off];
    __syncthreads();
  }
  if (threadIdx.x == 0) sc[SC_BSUM + blockIdx.x] = s[0];
}

// ---------------------------------------------------------------------------
// CSR build stage 2b: exclusive scan of the 196 block sums (single block).
// ---------------------------------------------------------------------------
__global__ __launch_bounds__(256) void scan2_kernel(int* __restrict__ sc) {
  __shared__ int s[2][256];
  const int t = threadIdx.x;
  const int v = (t < NBLK_SCAN) ? sc[SC_BSUM + t] : 0;
  int cur = 0;
  s[0][t] = v;
  __syncthreads();
  for (int off = 1; off < 256; off <<= 1) {
    int nv = s[cur][t];
    if (t >= off) nv += s[cur][t - off];
    s[cur ^ 1][t] = nv;
    cur ^= 1;
    __syncthreads();
  }
  if (t < NBLK_SCAN) sc[SC_BSUM + t] = s[cur][t] - v;  // inclusive -> exclusive
}

// ---------------------------------------------------------------------------
// CSR build stage 2c: full exclusive scan -> off[] and cur[].
// ---------------------------------------------------------------------------
__global__ __launch_bounds__(256) void scan3_kernel(int* __restrict__ sc) {
  __shared__ int s[2][256];
  const int t = threadIdx.x;
  const int i = blockIdx.x * 256 + t;
  const int v = (i < N_NODES) ? sc[SC_CNT + i] : 0;
  int cur = 0;
  s[0][t] = v;
  __syncthreads();
  for (int off = 1; off < 256; off <<= 1) {
    int nv = s[cur][t];
    if (t >= off) nv += s[cur][t - off];
    s[cur ^ 1][t] = nv;
    cur ^= 1;
    __syncthreads();
  }
  if (i < N_NODES) {
    const int excl = sc[SC_BSUM + blockIdx.x] + s[cur][t] - v;
    sc[SC_OFF + i] = excl;
    sc[SC_CUR + i] = excl;
  }
  if (i == 0) sc[SC_OFF + N_NODES] = N_EDGES;
}

// ---------------------------------------------------------------------------
// CSR build stage 3: fill edge-id lists (sorted by destination).
// ---------------------------------------------------------------------------
__global__ __launch_bounds__(256) void fill_kernel(const int* __restrict__ ei,
                                                   int* __restrict__ sc) {
  int e = blockIdx.x * 256 + threadIdx.x;
  if (e < N_EDGES) {
    const int d = ei[N_EDGES + e];
    const int pos = atomicAdd(&sc[SC_CUR + d], 1);
    sc[SC_EIDX + pos] = e;
  }
}

// ---------------------------------------------------------------------------
// Gather: agg[n] = sum of edge_attr rows with dst == n. Atomic-free.
// Block = 192 threads = 8 nodes x 24 float4-chunks; each edge-row read is a
// fully coalesced 384B burst across 24 lanes. eidx prefetched one iteration
// ahead to break the load-load dependency chain.
// ---------------------------------------------------------------------------
__global__ __launch_bounds__(192) void gather_kernel(
    const float* __restrict__ ea, const int* __restrict__ sc,
    float* __restrict__ agg) {
  const int t = threadIdx.x;
  const int ln = t / 24;
  const int q = t - ln * 24;
  const int n = blockIdx.x * 8 + ln;
  const int beg = sc[SC_OFF + n];
  const int end = sc[SC_OFF + n + 1];
  float4 acc = make_float4(0.f, 0.f, 0.f, 0.f);
  int e = (beg < end) ? sc[SC_EIDX + beg] : 0;
  for (int i = beg; i < end; ++i) {
    const int en = (i + 1 < end) ? sc[SC_EIDX + i + 1] : 0;
    const float4 v =
        *reinterpret_cast<const float4*>(ea + (size_t)e * DIM + q * 4);
    acc.x += v.x;
    acc.y += v.y;
    acc.z += v.z;
    acc.w += v.w;
    e = en;
  }
  *reinterpret_cast<float4*>(agg + (size_t)n * DIM + q * 4) = acc;
}

// ---------------------------------------------------------------------------
// Copy edge_index to output as floats.
// ---------------------------------------------------------------------------
__global__ __launch_bounds__(256) void copy_ei_kernel(
    const int* __restrict__ ei, float* __restrict__ out) {
  int tid = blockIdx.x * 256 + threadIdx.x;
  if (tid < 2 * N_EDGES) out[tid] = (float)ei[tid];
}

// ---------------------------------------------------------------------------
// Node MLP as register-tiled GEMM. K=192 (x || agg), fused 2 layers.
// ---------------------------------------------------------------------------
__global__ __launch_bounds__(256, 2) void node_mlp_kernel(
    const float* __restrict__ x, const float* __restrict__ agg,
    const float* __restrict__ W1, const float* __restrict__ b1,
    const float* __restrict__ W2, const float* __restrict__ b2,
    float* __restrict__ out) {
  __shared__ float As[BM * APAD];   // 13.3 KB
  __shared__ float Ws[BK * DIM];    // 18.0 KB
  __shared__ float Hs[BM * HPAD];   // 25.6 KB

  const int t = threadIdx.x;
  const int tx = t & 7;
  const int ty = t >> 3;
  const int r0 = ty * 2;
  const int n0 = blockIdx.x * BM;
  const int cbase = tx * 12;

  float4 c00 = make_float4(0.f, 0.f, 0.f, 0.f);
  float4 c01 = c00, c02 = c00, c10 = c00, c11 = c00, c12 = c00;

  // ----- layer 1: acc = A[64 x 192] @ W1[192 x 96], K-chunks of 48 -----
  for (int ch = 0; ch < 4; ++ch) {
    const int k0 = ch * BK;
    __syncthreads();
#pragma unroll
    for (int m = 0; m < 3; ++m) {
      const int idx = m * 256 + t;
      const int row = idx / 12;
      const int c4 = (idx - row * 12) * 4;
      const int col = k0 + c4;
      int n = n0 + row;
      n = (n < N_NODES) ? n : 0;  // clamp; garbage rows never stored
      const float* src = (col < DIM) ? x + (size_t)n * DIM + col
                                     : agg + (size_t)n * DIM + (col - DIM);
      *reinterpret_cast<float4*>(&As[row * APAD + c4]) =
          *reinterpret_cast<const float4*>(src);
    }
#pragma unroll
    for (int m = 0; m < 5; ++m) {
      const int idx = m * 256 + t;
      if (idx < (BK * DIM) / 4) {
        const int wr = idx / 24;
        const int wc = (idx - wr * 24) * 4;
        *reinterpret_cast<float4*>(&Ws[wr * DIM + wc]) =
            *reinterpret_cast<const float4*>(W1 + (size_t)(k0 + wr) * DIM + wc);
      }
    }
    __syncthreads();
#pragma unroll 4
    for (int k = 0; k < BK; ++k) {
      const float a0 = As[(r0 + 0) * APAD + k];
      const float a1 = As[(r0 + 1) * APAD + k];
      const float4 w0 =
          *reinterpret_cast<const float4*>(&Ws[k * DIM + cbase + 0]);
      const float4 w1 =
          *reinterpret_cast<const float4*>(&Ws[k * DIM + cbase + 4]);
      const float4 w2 =
          *reinterpret_cast<const float4*>(&Ws[k * DIM + cbase + 8]);
      FMA4(c00, a0, w0);
      FMA4(c01, a0, w1);
      FMA4(c02, a0, w2);
      FMA4(c10, a1, w0);
      FMA4(c11, a1, w1);
      FMA4(c12, a1, w2);
    }
  }

  {
    const float4 bb0 = *reinterpret_cast<const float4*>(b1 + cbase + 0);
    const float4 bb1 = *reinterpret_cast<const float4*>(b1 + cbase + 4);
    const float4 bb2 = *reinterpret_cast<const float4*>(b1 + cbase + 8);
    BIAS_RELU4(c00, bb0);
    BIAS_RELU4(c01, bb1);
    BIAS_RELU4(c02, bb2);
    BIAS_RELU4(c10, bb0);
    BIAS_RELU4(c11, bb1);
    BIAS_RELU4(c12, bb2);
    *reinterpret_cast<float4*>(&Hs[(r0 + 0) * HPAD + cbase + 0]) = c00;
    *reinterpret_cast<float4*>(&Hs[(r0 + 0) * HPAD + cbase + 4]) = c01;
    *reinterpret_cast<float4*>(&Hs[(r0 + 0) * HPAD + cbase + 8]) = c02;
    *reinterpret_cast<float4*>(&Hs[(r0 + 1) * HPAD + cbase + 0]) = c10;
    *reinterpret_cast<float4*>(&Hs[(r0 + 1) * HPAD + cbase + 4]) = c11;
    *reinterpret_cast<float4*>(&Hs[(r0 + 1) * HPAD + cbase + 8]) = c12;
  }

  // ----- layer 2: out = relu_h[64 x 96] @ W2[96 x 96] -----
  c00 = make_float4(0.f, 0.f, 0.f, 0.f);
  c01 = c00;
  c02 = c00;
  c10 = c00;
  c11 = c00;
  c12 = c00;
  for (int ch = 0; ch < 2; ++ch) {
    const int k0 = ch * BK;
    __syncthreads();
#pragma unroll
    for (int m = 0; m < 5; ++m) {
      const int idx = m * 256 + t;
      if (idx < (BK * DIM) / 4) {
        const int wr = idx / 24;
        const int wc = (idx - wr * 24) * 4;
        *reinterpret_cast<float4*>(&Ws[wr * DIM + wc]) =
            *reinterpret_cast<const float4*>(W2 + (size_t)(k0 + wr) * DIM + wc);
      }
    }
    __syncthreads();
#pragma unroll 4
    for (int k = 0; k < BK; ++k) {
      const float a0 = Hs[(r0 + 0) * HPAD + k0 + k];
      const float a1 = Hs[(r0 + 1) * HPAD + k0 + k];
      const float4 w0 =
          *reinterpret_cast<const float4*>(&Ws[k * DIM + cbase + 0]);
      const float4 w1 =
          *reinterpret_cast<const float4*>(&Ws[k * DIM + cbase + 4]);
      const float4 w2 =
          *reinterpret_cast<const float4*>(&Ws[k * DIM + cbase + 8]);
      FMA4(c00, a0, w0);
      FMA4(c01, a0, w1);
      FMA4(c02, a0, w2);
      FMA4(c10, a1, w0);
      FMA4(c11, a1, w1);
      FMA4(c12, a1, w2);
    }
  }

  {
    const float4 bb0 = *reinterpret_cast<const float4*>(b2 + cbase + 0);
    const float4 bb1 = *reinterpret_cast<const float4*>(b2 + cbase + 4);
    const float4 bb2 = *reinterpret_cast<const float4*>(b2 + cbase + 8);
    BIAS4(c00, bb0);
    BIAS4(c01, bb1);
    BIAS4(c02, bb2);
    BIAS4(c10, bb0);
    BIAS4(c11, bb1);
    BIAS4(c12, bb2);
    const int n_r0 = n0 + r0;
    if (n_r0 < N_NODES) {
      float* o = out + (size_t)n_r0 * DIM + cbase;
      *reinterpret_cast<float4*>(o + 0) = c00;
      *reinterpret_cast<float4*>(o + 4) = c01;
      *reinterpret_cast<float4*>(o + 8) = c02;
    }
    if (n_r0 + 1 < N_NODES) {
      float* o = out + (size_t)(n_r0 + 1) * DIM + cbase;
      *reinterpret_cast<float4*>(o + 0) = c10;
      *reinterpret_cast<float4*>(o + 4) = c11;
      *reinterpret_cast<float4*>(o + 8) = c12;
    }
  }
}

// ---------------------------------------------------------------------------
// Edge MLP as register-tiled GEMM. K=288 (x[src] || x[dst] || ea).
// N_EDGES % 64 == 0, so no row guards. Runs LAST: overwrites CSR scratch.
// ---------------------------------------------------------------------------
__global__ __launch_bounds__(256, 2) void edge_mlp_kernel(
    const float* __restrict__ x, const int* __restrict__ ei,
    const float* __restrict__ ea, const float* __restrict__ W1,
    const float* __restrict__ b1, const float* __restrict__ W2,
    const float* __restrict__ b2, float* __restrict__ out) {
  __shared__ int s_src[BM];
  __shared__ int s_dst[BM];
  __shared__ float As[BM * APAD];
  __shared__ float Ws[BK * DIM];
  __shared__ float Hs[BM * HPAD];

  const int t = threadIdx.x;
  const int tx = t & 7;
  const int ty = t >> 3;
  const int r0 = ty * 2;
  const int e0 = blockIdx.x * BM;
  const int cbase = tx * 12;

  if (t < BM) {
    s_src[t] = ei[e0 + t];
    s_dst[t] = ei[N_EDGES + e0 + t];
  }

  float4 c00 = make_float4(0.f, 0.f, 0.f, 0.f);
  float4 c01 = c00, c02 = c00, c10 = c00, c11 = c00, c12 = c00;

  // ----- layer 1: K = 288, 6 chunks of 48. Each chunk lies entirely within
  // one concat segment (chunks 0-1: x[src], 2-3: x[dst], 4-5: ea). -----
  for (int ch = 0; ch < 6; ++ch) {
    const int k0 = ch * BK;
    __syncthreads();  // also covers the s_src/s_dst writes on ch==0
#pragma unroll
    for (int m = 0; m < 3; ++m) {
      const int idx = m * 256 + t;
      const int row = idx / 12;
      const int c4 = (idx - row * 12) * 4;
      const int col = k0 + c4;
      const float* src;
      if (col < DIM)
        src = x + (size_t)s_src[row] * DIM + col;
      else if (col < 2 * DIM)
        src = x + (size_t)s_dst[row] * DIM + (col - DIM);
      else
        src = ea + (size_t)(e0 + row) * DIM + (col - 2 * DIM);
      *reinterpret_cast<float4*>(&As[row * APAD + c4]) =
          *reinterpret_cast<const float4*>(src);
    }
#pragma unroll
    for (int m = 0; m < 5; ++m) {
      const int idx = m * 256 + t;
      if (idx < (BK * DIM) / 4) {
        const int wr = idx / 24;
        const int wc = (idx - wr * 24) * 4;
        *reinterpret_cast<float4*>(&Ws[wr * DIM + wc]) =
            *reinterpret_cast<const float4*>(W1 + (size_t)(k0 + wr) * DIM + wc);
      }
    }
    __syncthreads();
#pragma unroll 4
    for (int k = 0; k < BK; ++k) {
      const float a0 = As[(r0 + 0) * APAD + k];
      const float a1 = As[(r0 + 1) * APAD + k];
      const float4 w0 =
          *reinterpret_cast<const float4*>(&Ws[k * DIM + cbase + 0]);
      const float4 w1 =
          *reinterpret_cast<const float4*>(&Ws[k * DIM + cbase + 4]);
      const float4 w2 =
          *reinterpret_cast<const float4*>(&Ws[k * DIM + cbase + 8]);
      FMA4(c00, a0, w0);
      FMA4(c01, a0, w1);
      FMA4(c02, a0, w2);
      FMA4(c10, a1, w0);
      FMA4(c11, a1, w1);
      FMA4(c12, a1, w2);
    }
  }

  {
    const float4 bb0 = *reinterpret_cast<const float4*>(b1 + cbase + 0);
    const float4 bb1 = *reinterpret_cast<const float4*>(b1 + cbase + 4);
    const float4 bb2 = *reinterpret_cast<const float4*>(b1 + cbase + 8);
    BIAS_RELU4(c00, bb0);
    BIAS_RELU4(c01, bb1);
    BIAS_RELU4(c02, bb2);
    BIAS_RELU4(c10, bb0);
    BIAS_RELU4(c11, bb1);
    BIAS_RELU4(c12, bb2);
    *reinterpret_cast<float4*>(&Hs[(r0 + 0) * HPAD + cbase + 0]) = c00;
    *reinterpret_cast<float4*>(&Hs[(r0 + 0) * HPAD + cbase + 4]) = c01;
    *reinterpret_cast<float4*>(&Hs[(r0 + 0) * HPAD + cbase + 8]) = c02;
    *reinterpret_cast<float4*>(&Hs[(r0 + 1) * HPAD + cbase + 0]) = c10;
    *reinterpret_cast<float4*>(&Hs[(r0 + 1) * HPAD + cbase + 4]) = c11;
    *reinterpret_cast<float4*>(&Hs[(r0 + 1) * HPAD + cbase + 8]) = c12;
  }

  // ----- layer 2 -----
  c00 = make_float4(0.f, 0.f, 0.f, 0.f);
  c01 = c00;
  c02 = c00;
  c10 = c00;
  c11 = c00;
  c12 = c00;
  for (int ch = 0; ch < 2; ++ch) {
    const int k0 = ch * BK;
    __syncthreads();
#pragma unroll
    for (int m = 0; m < 5; ++m) {
      const int idx = m * 256 + t;
      if (idx < (BK * DIM) / 4) {
        const int wr = idx / 24;
        const int wc = (idx - wr * 24) * 4;
        *reinterpret_cast<float4*>(&Ws[wr * DIM + wc]) =
            *reinterpret_cast<const float4*>(W2 + (size_t)(k0 + wr) * DIM + wc);
      }
    }
    __syncthreads();
#pragma unroll 4
    for (int k = 0; k < BK; ++k) {
      const float a0 = Hs[(r0 + 0) * HPAD + k0 + k];
      const float a1 = Hs[(r0 + 1) * HPAD + k0 + k];
      const float4 w0 =
          *reinterpret_cast<const float4*>(&Ws[k * DIM + cbase + 0]);
      const float4 w1 =
          *reinterpret_cast<const float4*>(&Ws[k * DIM + cbase + 4]);
      const float4 w2 =
          *reinterpret_cast<const float4*>(&Ws[k * DIM + cbase + 8]);
      FMA4(c00, a0, w0);
      FMA4(c01, a0, w1);
      FMA4(c02, a0, w2);
      FMA4(c10, a1, w0);
      FMA4(c11, a1, w1);
      FMA4(c12, a1, w2);
    }
  }

  {
    const float4 bb0 = *reinterpret_cast<const float4*>(b2 + cbase + 0);
    const float4 bb1 = *reinterpret_cast<const float4*>(b2 + cbase + 4);
    const float4 bb2 = *reinterpret_cast<const float4*>(b2 + cbase + 8);
    BIAS4(c00, bb0);
    BIAS4(c01, bb1);
    BIAS4(c02, bb2);
    BIAS4(c10, bb0);
    BIAS4(c11, bb1);
    BIAS4(c12, bb2);
    float* o0 = out + (size_t)(e0 + r0) * DIM + cbase;
    float* o1 = out + (size_t)(e0 + r0 + 1) * DIM + cbase;
    *reinterpret_cast<float4*>(o0 + 0) = c00;
    *reinterpret_cast<float4*>(o0 + 4) = c01;
    *reinterpret_cast<float4*>(o0 + 8) = c02;
    *reinterpret_cast<float4*>(o1 + 0) = c10;
    *reinterpret_cast<float4*>(o1 + 4) = c11;
    *reinterpret_cast<float4*>(o1 + 8) = c12;
  }
}

// ---------------------------------------------------------------------------
extern "C" void kernel_launch(void* const* d_in, const int* in_sizes, int n_in,
                              void* d_out, int out_size, void* d_ws,
                              size_t ws_size, hipStream_t stream) {
  const float* x = (const float*)d_in[0];
  const int* ei = (const int*)d_in[1];
  const float* edge_attr = (const float*)d_in[2];
  const float* Wn1 = (const float*)d_in[3];
  const float* bn1 = (const float*)d_in[4];
  const float* Wn2 = (const float*)d_in[5];
  const float* bn2 = (const float*)d_in[6];
  const float* We1 = (const float*)d_in[7];
  const float* be1 = (const float*)d_in[8];
  const float* We2 = (const float*)d_in[9];
  const float* be2 = (const float*)d_in[10];

  float* out = (float*)d_out;
  float* agg = (float*)d_ws;  // [N_NODES, DIM] fp32 scratch = 19.2 MB

  float* out_hv = out;
  float* out_ei = out + (size_t)N_NODES * DIM;
  float* out_he = out + (size_t)N_NODES * DIM + 2 * (size_t)N_EDGES;

  // CSR scratch lives in the out_he region (< 4 MB of its 307 MB); the
  // edge_mlp_kernel runs last and overwrites the entire region with h_e.
  int* sc = (int*)out_he;

  hipMemsetAsync(sc + SC_CNT, 0, N_NODES * sizeof(int), stream);
  hist_kernel<<<(N_EDGES + 255) / 256, 256, 0, stream>>>(ei, sc);
  scan1_kernel<<<NBLK_SCAN, 256, 0, stream>>>(sc);
  scan2_kernel<<<1, 256, 0, stream>>>(sc);
  scan3_kernel<<<NBLK_SCAN, 256, 0, stream>>>(sc);
  fill_kernel<<<(N_EDGES + 255) / 256, 256, 0, stream>>>(ei, sc);
  gather_kernel<<<N_NODES / 8, 192, 0, stream>>>(edge_attr, sc, agg);

  copy_ei_kernel<<<(2 * N_EDGES + 255) / 256, 256, 0, stream>>>(ei, out_ei);
  node_mlp_kernel<<<(N_NODES + BM - 1) / BM, 256, 0, stream>>>(
      x, agg, Wn1, bn1, Wn2, bn2, out_hv);
  edge_mlp_kernel<<<N_EDGES / BM, 256, 0, stream>>>(x, ei, edge_attr, We1, be1,
                                                    We2, be2, out_he);
}

// Round 5
// 1649.258 us; speedup vs baseline: 3.1596x; 1.0375x over previous
//
#include <hip/hip_runtime.h>

#define N_NODES 50000
#define N_EDGES 800000
#define DIM 96

// GEMM tile geometry: 256 threads, 64-row x 96-col output tile.
// thread (tx = t&7, ty = t>>3) owns rows {2ty, 2ty+1} x cols [12tx, 12tx+12).
#define BM 64
#define BK 48
#define APAD 52   // A row stride (floats): 208B, 16B-aligned; 2-row read stride 2-way bank-aliased (free).
#define HPAD 100  // H row stride (floats): 400B, 16B-aligned; 2-way aliased (free).

// CSR scratch layout (int offsets) inside the out_he region, which is
// overwritten by edge_mlp_kernel at the very end of the launch sequence.
#define SC_CNT 0           // [50000) histogram / per-node degree
#define SC_OFF 50000       // [50001) exclusive prefix (CSR row offsets)
#define SC_CUR 100016      // [50000) fill cursors
#define SC_BSUM 150016     // [256)   per-block partial sums for the scan
#define SC_EIDX 150528     // [800000) edge ids sorted by destination
#define NBLK_SCAN 196      // ceil(50000/256)

#define FMA4(C, A, W)        \
  C.x = fmaf(A, W.x, C.x);   \
  C.y = fmaf(A, W.y, C.y);   \
  C.z = fmaf(A, W.z, C.z);   \
  C.w = fmaf(A, W.w, C.w)

#define BIAS_RELU4(C, B)          \
  C.x = fmaxf(C.x + B.x, 0.0f);   \
  C.y = fmaxf(C.y + B.y, 0.0f);   \
  C.z = fmaxf(C.z + B.z, 0.0f);   \
  C.w = fmaxf(C.w + B.w, 0.0f)

#define BIAS4(C, B) \
  C.x += B.x;       \
  C.y += B.y;       \
  C.z += B.z;       \
  C.w += B.w

// One k-step of the 2-row x 12-col register tile; A0/A1 are scalars from the
// float4 A fragments, W rows come from LDS as float4 (all b128 traffic).
#define KSTEP(KK, A0, A1)                                                    \
  {                                                                          \
    const float4 w0 =                                                        \
        *reinterpret_cast<const float4*>(&Ws[(k + KK) * DIM + cbase + 0]);   \
    const float4 w1 =                                                        \
        *reinterpret_cast<const float4*>(&Ws[(k + KK) * DIM + cbase + 4]);   \
    const float4 w2 =                                                        \
        *reinterpret_cast<const float4*>(&Ws[(k + KK) * DIM + cbase + 8]);   \
    FMA4(c00, A0, w0);                                                       \
    FMA4(c01, A0, w1);                                                       \
    FMA4(c02, A0, w2);                                                       \
    FMA4(c10, A1, w0);                                                       \
    FMA4(c11, A1, w1);                                                       \
    FMA4(c12, A1, w2);                                                       \
  }

// ---------------------------------------------------------------------------
// CSR build stage 1: per-destination histogram.
// ---------------------------------------------------------------------------
__global__ __launch_bounds__(256) void hist_kernel(const int* __restrict__ ei,
                                                   int* __restrict__ sc) {
  int e = blockIdx.x * 256 + threadIdx.x;
  if (e < N_EDGES) atomicAdd(&sc[SC_CNT + ei[N_EDGES + e]], 1);
}

// ---------------------------------------------------------------------------
// CSR build stage 2a: per-block sums of the histogram.
// ---------------------------------------------------------------------------
__global__ __launch_bounds__(256) void scan1_kernel(int* __restrict__ sc) {
  __shared__ int s[256];
  int i = blockIdx.x * 256 + threadIdx.x;
  s[threadIdx.x] = (i < N_NODES) ? sc[SC_CNT + i] : 0;
  __syncthreads();
  for (int off = 128; off > 0; off >>= 1) {
    if (threadIdx.x < off) s[threadIdx.x] += s[threadIdx.x + off];
    __syncthreads();
  }
  if (threadIdx.x == 0) sc[SC_BSUM + blockIdx.x] = s[0];
}

// ---------------------------------------------------------------------------
// CSR build stage 2b: exclusive scan of the 196 block sums (single block).
// ---------------------------------------------------------------------------
__global__ __launch_bounds__(256) void scan2_kernel(int* __restrict__ sc) {
  __shared__ int s[2][256];
  const int t = threadIdx.x;
  const int v = (t < NBLK_SCAN) ? sc[SC_BSUM + t] : 0;
  int cur = 0;
  s[0][t] = v;
  __syncthreads();
  for (int off = 1; off < 256; off <<= 1) {
    int nv = s[cur][t];
    if (t >= off) nv += s[cur][t - off];
    s[cur ^ 1][t] = nv;
    cur ^= 1;
    __syncthreads();
  }
  if (t < NBLK_SCAN) sc[SC_BSUM + t] = s[cur][t] - v;  // inclusive -> exclusive
}

// ---------------------------------------------------------------------------
// CSR build stage 2c: full exclusive scan -> off[] and cur[].
// ---------------------------------------------------------------------------
__global__ __launch_bounds__(256) void scan3_kernel(int* __restrict__ sc) {
  __shared__ int s[2][256];
  const int t = threadIdx.x;
  const int i = blockIdx.x * 256 + t;
  const int v = (i < N_NODES) ? sc[SC_CNT + i] : 0;
  int cur = 0;
  s[0][t] = v;
  __syncthreads();
  for (int off = 1; off < 256; off <<= 1) {
    int nv = s[cur][t];
    if (t >= off) nv += s[cur][t - off];
    s[cur ^ 1][t] = nv;
    cur ^= 1;
    __syncthreads();
  }
  if (i < N_NODES) {
    const int excl = sc[SC_BSUM + blockIdx.x] + s[cur][t] - v;
    sc[SC_OFF + i] = excl;
    sc[SC_CUR + i] = excl;
  }
  if (i == 0) sc[SC_OFF + N_NODES] = N_EDGES;
}

// ---------------------------------------------------------------------------
// CSR build stage 3: fill edge-id lists (sorted by destination).
// ---------------------------------------------------------------------------
__global__ __launch_bounds__(256) void fill_kernel(const int* __restrict__ ei,
                                                   int* __restrict__ sc) {
  int e = blockIdx.x * 256 + threadIdx.x;
  if (e < N_EDGES) {
    const int d = ei[N_EDGES + e];
    const int pos = atomicAdd(&sc[SC_CUR + d], 1);
    sc[SC_EIDX + pos] = e;
  }
}

// ---------------------------------------------------------------------------
// Gather: agg[n] = sum of edge_attr rows with dst == n. Atomic-free.
// 192 threads = 8 nodes x 24 float4-chunks; edge-id prefetched one iteration
// ahead to break the load-load dependency chain.
// ---------------------------------------------------------------------------
__global__ __launch_bounds__(192) void gather_kernel(
    const float* __restrict__ ea, const int* __restrict__ sc,
    float* __restrict__ agg) {
  const int t = threadIdx.x;
  const int ln = t / 24;
  const int q = t - ln * 24;
  const int n = blockIdx.x * 8 + ln;
  const int beg = sc[SC_OFF + n];
  const int end = sc[SC_OFF + n + 1];
  float4 acc = make_float4(0.f, 0.f, 0.f, 0.f);
  int e = (beg < end) ? sc[SC_EIDX + beg] : 0;
  for (int i = beg; i < end; ++i) {
    const int en = (i + 1 < end) ? sc[SC_EIDX + i + 1] : 0;
    const float4 v =
        *reinterpret_cast<const float4*>(ea + (size_t)e * DIM + q * 4);
    acc.x += v.x;
    acc.y += v.y;
    acc.z += v.z;
    acc.w += v.w;
    e = en;
  }
  *reinterpret_cast<float4*>(agg + (size_t)n * DIM + q * 4) = acc;
}

// ---------------------------------------------------------------------------
// Copy edge_index to output as floats.
// ---------------------------------------------------------------------------
__global__ __launch_bounds__(256) void copy_ei_kernel(
    const int* __restrict__ ei, float* __restrict__ out) {
  int tid = blockIdx.x * 256 + threadIdx.x;
  if (tid < 2 * N_EDGES) out[tid] = (float)ei[tid];
}

// ---------------------------------------------------------------------------
// Node MLP as register-tiled GEMM. K=192 (x || agg), fused 2 layers.
// AH buffer: A-tile (APAD stride) in layer 1, H-tile (HPAD stride) in layer 2.
// LDS = (48*96 + 64*100)*4 = 44 KB -> 3 blocks/CU.
// ---------------------------------------------------------------------------
__global__ __launch_bounds__(256, 3) void node_mlp_kernel(
    const float* __restrict__ x, const float* __restrict__ agg,
    const float* __restrict__ W1, const float* __restrict__ b1,
    const float* __restrict__ W2, const float* __restrict__ b2,
    float* __restrict__ out) {
  __shared__ float Ws[BK * DIM];    // 18.0 KB
  __shared__ float AH[BM * HPAD];   // 25.6 KB (A view: APAD stride; H view: HPAD)

  const int t = threadIdx.x;
  const int tx = t & 7;
  const int ty = t >> 3;
  const int r0 = ty * 2;
  const int n0 = blockIdx.x * BM;
  const int cbase = tx * 12;

  float4 c00 = make_float4(0.f, 0.f, 0.f, 0.f);
  float4 c01 = c00, c02 = c00, c10 = c00, c11 = c00, c12 = c00;

  // ----- layer 1: acc = A[64 x 192] @ W1[192 x 96], K-chunks of 48 -----
  for (int ch = 0; ch < 4; ++ch) {
    const int k0 = ch * BK;
    __syncthreads();
#pragma unroll
    for (int m = 0; m < 3; ++m) {
      const int idx = m * 256 + t;
      const int row = idx / 12;
      const int c4 = (idx - row * 12) * 4;
      const int col = k0 + c4;
      int n = n0 + row;
      n = (n < N_NODES) ? n : 0;  // clamp; garbage rows never stored
      const float* src = (col < DIM) ? x + (size_t)n * DIM + col
                                     : agg + (size_t)n * DIM + (col - DIM);
      *reinterpret_cast<float4*>(&AH[row * APAD + c4]) =
          *reinterpret_cast<const float4*>(src);
    }
#pragma unroll
    for (int m = 0; m < 5; ++m) {
      const int idx = m * 256 + t;
      if (idx < (BK * DIM) / 4) {
        const int wr = idx / 24;
        const int wc = (idx - wr * 24) * 4;
        *reinterpret_cast<float4*>(&Ws[wr * DIM + wc]) =
            *reinterpret_cast<const float4*>(W1 + (size_t)(k0 + wr) * DIM + wc);
      }
    }
    __syncthreads();
#pragma unroll
    for (int k = 0; k < BK; k += 4) {
      const float4 a0v =
          *reinterpret_cast<const float4*>(&AH[(r0 + 0) * APAD + k]);
      const float4 a1v =
          *reinterpret_cast<const float4*>(&AH[(r0 + 1) * APAD + k]);
      KSTEP(0, a0v.x, a1v.x);
      KSTEP(1, a0v.y, a1v.y);
      KSTEP(2, a0v.z, a1v.z);
      KSTEP(3, a0v.w, a1v.w);
    }
  }

  __syncthreads();  // all A reads done before H overwrites the buffer

  {
    const float4 bb0 = *reinterpret_cast<const float4*>(b1 + cbase + 0);
    const float4 bb1 = *reinterpret_cast<const float4*>(b1 + cbase + 4);
    const float4 bb2 = *reinterpret_cast<const float4*>(b1 + cbase + 8);
    BIAS_RELU4(c00, bb0);
    BIAS_RELU4(c01, bb1);
    BIAS_RELU4(c02, bb2);
    BIAS_RELU4(c10, bb0);
    BIAS_RELU4(c11, bb1);
    BIAS_RELU4(c12, bb2);
    *reinterpret_cast<float4*>(&AH[(r0 + 0) * HPAD + cbase + 0]) = c00;
    *reinterpret_cast<float4*>(&AH[(r0 + 0) * HPAD + cbase + 4]) = c01;
    *reinterpret_cast<float4*>(&AH[(r0 + 0) * HPAD + cbase + 8]) = c02;
    *reinterpret_cast<float4*>(&AH[(r0 + 1) * HPAD + cbase + 0]) = c10;
    *reinterpret_cast<float4*>(&AH[(r0 + 1) * HPAD + cbase + 4]) = c11;
    *reinterpret_cast<float4*>(&AH[(r0 + 1) * HPAD + cbase + 8]) = c12;
  }

  // ----- layer 2: out = relu_h[64 x 96] @ W2[96 x 96] -----
  c00 = make_float4(0.f, 0.f, 0.f, 0.f);
  c01 = c00;
  c02 = c00;
  c10 = c00;
  c11 = c00;
  c12 = c00;
  for (int ch = 0; ch < 2; ++ch) {
    const int k0 = ch * BK;
    __syncthreads();  // H writes visible; previous Ws readers done
#pragma unroll
    for (int m = 0; m < 5; ++m) {
      const int idx = m * 256 + t;
      if (idx < (BK * DIM) / 4) {
        const int wr = idx / 24;
        const int wc = (idx - wr * 24) * 4;
        *reinterpret_cast<float4*>(&Ws[wr * DIM + wc]) =
            *reinterpret_cast<const float4*>(W2 + (size_t)(k0 + wr) * DIM + wc);
      }
    }
    __syncthreads();
#pragma unroll
    for (int k = 0; k < BK; k += 4) {
      const float4 a0v =
          *reinterpret_cast<const float4*>(&AH[(r0 + 0) * HPAD + k0 + k]);
      const float4 a1v =
          *reinterpret_cast<const float4*>(&AH[(r0 + 1) * HPAD + k0 + k]);
      KSTEP(0, a0v.x, a1v.x);
      KSTEP(1, a0v.y, a1v.y);
      KSTEP(2, a0v.z, a1v.z);
      KSTEP(3, a0v.w, a1v.w);
    }
  }

  {
    const float4 bb0 = *reinterpret_cast<const float4*>(b2 + cbase + 0);
    const float4 bb1 = *reinterpret_cast<const float4*>(b2 + cbase + 4);
    const float4 bb2 = *reinterpret_cast<const float4*>(b2 + cbase + 8);
    BIAS4(c00, bb0);
    BIAS4(c01, bb1);
    BIAS4(c02, bb2);
    BIAS4(c10, bb0);
    BIAS4(c11, bb1);
    BIAS4(c12, bb2);
    const int n_r0 = n0 + r0;
    if (n_r0 < N_NODES) {
      float* o = out + (size_t)n_r0 * DIM + cbase;
      *reinterpret_cast<float4*>(o + 0) = c00;
      *reinterpret_cast<float4*>(o + 4) = c01;
      *reinterpret_cast<float4*>(o + 8) = c02;
    }
    if (n_r0 + 1 < N_NODES) {
      float* o = out + (size_t)(n_r0 + 1) * DIM + cbase;
      *reinterpret_cast<float4*>(o + 0) = c10;
      *reinterpret_cast<float4*>(o + 4) = c11;
      *reinterpret_cast<float4*>(o + 8) = c12;
    }
  }
}

// ---------------------------------------------------------------------------
// Edge MLP as register-tiled GEMM. K=288 (x[src] || x[dst] || ea).
// N_EDGES % 64 == 0, so no row guards. Runs LAST: overwrites CSR scratch.
// ---------------------------------------------------------------------------
__global__ __launch_bounds__(256, 3) void edge_mlp_kernel(
    const float* __restrict__ x, const int* __restrict__ ei,
    const float* __restrict__ ea, const float* __restrict__ W1,
    const float* __restrict__ b1, const float* __restrict__ W2,
    const float* __restrict__ b2, float* __restrict__ out) {
  __shared__ int s_src[BM];
  __shared__ int s_dst[BM];
  __shared__ float Ws[BK * DIM];    // 18.0 KB
  __shared__ float AH[BM * HPAD];   // 25.6 KB

  const int t = threadIdx.x;
  const int tx = t & 7;
  const int ty = t >> 3;
  const int r0 = ty * 2;
  const int e0 = blockIdx.x * BM;
  const int cbase = tx * 12;

  if (t < BM) {
    s_src[t] = ei[e0 + t];
    s_dst[t] = ei[N_EDGES + e0 + t];
  }

  float4 c00 = make_float4(0.f, 0.f, 0.f, 0.f);
  float4 c01 = c00, c02 = c00, c10 = c00, c11 = c00, c12 = c00;

  // ----- layer 1: K = 288, 6 chunks of 48. Each chunk lies entirely within
  // one concat segment (chunks 0-1: x[src], 2-3: x[dst], 4-5: ea). -----
  for (int ch = 0; ch < 6; ++ch) {
    const int k0 = ch * BK;
    __syncthreads();  // also covers the s_src/s_dst writes on ch==0
#pragma unroll
    for (int m = 0; m < 3; ++m) {
      const int idx = m * 256 + t;
      const int row = idx / 12;
      const int c4 = (idx - row * 12) * 4;
      const int col = k0 + c4;
      const float* src;
      if (col < DIM)
        src = x + (size_t)s_src[row] * DIM + col;
      else if (col < 2 * DIM)
        src = x + (size_t)s_dst[row] * DIM + (col - DIM);
      else
        src = ea + (size_t)(e0 + row) * DIM + (col - 2 * DIM);
      *reinterpret_cast<float4*>(&AH[row * APAD + c4]) =
          *reinterpret_cast<const float4*>(src);
    }
#pragma unroll
    for (int m = 0; m < 5; ++m) {
      const int idx = m * 256 + t;
      if (idx < (BK * DIM) / 4) {
        const int wr = idx / 24;
        const int wc = (idx - wr * 24) * 4;
        *reinterpret_cast<float4*>(&Ws[wr * DIM + wc]) =
            *reinterpret_cast<const float4*>(W1 + (size_t)(k0 + wr) * DIM + wc);
      }
    }
    __syncthreads();
#pragma unroll
    for (int k = 0; k < BK; k += 4) {
      const float4 a0v =
          *reinterpret_cast<const float4*>(&AH[(r0 + 0) * APAD + k]);
      const float4 a1v =
          *reinterpret_cast<const float4*>(&AH[(r0 + 1) * APAD + k]);
      KSTEP(0, a0v.x, a1v.x);
      KSTEP(1, a0v.y, a1v.y);
      KSTEP(2, a0v.z, a1v.z);
      KSTEP(3, a0v.w, a1v.w);
    }
  }

  __syncthreads();  // all A reads done before H overwrites the buffer

  {
    const float4 bb0 = *reinterpret_cast<const float4*>(b1 + cbase + 0);
    const float4 bb1 = *reinterpret_cast<const float4*>(b1 + cbase + 4);
    const float4 bb2 = *reinterpret_cast<const float4*>(b1 + cbase + 8);
    BIAS_RELU4(c00, bb0);
    BIAS_RELU4(c01, bb1);
    BIAS_RELU4(c02, bb2);
    BIAS_RELU4(c10, bb0);
    BIAS_RELU4(c11, bb1);
    BIAS_RELU4(c12, bb2);
    *reinterpret_cast<float4*>(&AH[(r0 + 0) * HPAD + cbase + 0]) = c00;
    *reinterpret_cast<float4*>(&AH[(r0 + 0) * HPAD + cbase + 4]) = c01;
    *reinterpret_cast<float4*>(&AH[(r0 + 0) * HPAD + cbase + 8]) = c02;
    *reinterpret_cast<float4*>(&AH[(r0 + 1) * HPAD + cbase + 0]) = c10;
    *reinterpret_cast<float4*>(&AH[(r0 + 1) * HPAD + cbase + 4]) = c11;
    *reinterpret_cast<float4*>(&AH[(r0 + 1) * HPAD + cbase + 8]) = c12;
  }

  // ----- layer 2 -----
  c00 = make_float4(0.f, 0.f, 0.f, 0.f);
  c01 = c00;
  c02 = c00;
  c10 = c00;
  c11 = c00;
  c12 = c00;
  for (int ch = 0; ch < 2; ++ch) {
    const int k0 = ch * BK;
    __syncthreads();
#pragma unroll
    for (int m = 0; m < 5; ++m) {
      const int idx = m * 256 + t;
      if (idx < (BK * DIM) / 4) {
        const int wr = idx / 24;
        const int wc = (idx - wr * 24) * 4;
        *reinterpret_cast<float4*>(&Ws[wr * DIM + wc]) =
            *reinterpret_cast<const float4*>(W2 + (size_t)(k0 + wr) * DIM + wc);
      }
    }
    __syncthreads();
#pragma unroll
    for (int k = 0; k < BK; k += 4) {
      const float4 a0v =
          *reinterpret_cast<const float4*>(&AH[(r0 + 0) * HPAD + k0 + k]);
      const float4 a1v =
          *reinterpret_cast<const float4*>(&AH[(r0 + 1) * HPAD + k0 + k]);
      KSTEP(0, a0v.x, a1v.x);
      KSTEP(1, a0v.y, a1v.y);
      KSTEP(2, a0v.z, a1v.z);
      KSTEP(3, a0v.w, a1v.w);
    }
  }

  {
    const float4 bb0 = *reinterpret_cast<const float4*>(b2 + cbase + 0);
    const float4 bb1 = *reinterpret_cast<const float4*>(b2 + cbase + 4);
    const float4 bb2 = *reinterpret_cast<const float4*>(b2 + cbase + 8);
    BIAS4(c00, bb0);
    BIAS4(c01, bb1);
    BIAS4(c02, bb2);
    BIAS4(c10, bb0);
    BIAS4(c11, bb1);
    BIAS4(c12, bb2);
    float* o0 = out + (size_t)(e0 + r0) * DIM + cbase;
    float* o1 = out + (size_t)(e0 + r0 + 1) * DIM + cbase;
    *reinterpret_cast<float4*>(o0 + 0) = c00;
    *reinterpret_cast<float4*>(o0 + 4) = c01;
    *reinterpret_cast<float4*>(o0 + 8) = c02;
    *reinterpret_cast<float4*>(o1 + 0) = c10;
    *reinterpret_cast<float4*>(o1 + 4) = c11;
    *reinterpret_cast<float4*>(o1 + 8) = c12;
  }
}

// ---------------------------------------------------------------------------
extern "C" void kernel_launch(void* const* d_in, const int* in_sizes, int n_in,
                              void* d_out, int out_size, void* d_ws,
                              size_t ws_size, hipStream_t stream) {
  const float* x = (const float*)d_in[0];
  const int* ei = (const int*)d_in[1];
  const float* edge_attr = (const float*)d_in[2];
  const float* Wn1 = (const float*)d_in[3];
  const float* bn1 = (const float*)d_in[4];
  const float* Wn2 = (const float*)d_in[5];
  const float* bn2 = (const float*)d_in[6];
  const float* We1 = (const float*)d_in[7];
  const float* be1 = (const float*)d_in[8];
  const float* We2 = (const float*)d_in[9];
  const float* be2 = (const float*)d_in[10];

  float* out = (float*)d_out;
  float* agg = (float*)d_ws;  // [N_NODES, DIM] fp32 scratch = 19.2 MB

  float* out_hv = out;
  float* out_ei = out + (size_t)N_NODES * DIM;
  float* out_he = out + (size_t)N_NODES * DIM + 2 * (size_t)N_EDGES;

  // CSR scratch lives in the out_he region (< 4 MB of its 307 MB); the
  // edge_mlp_kernel runs last and overwrites the entire region with h_e.
  int* sc = (int*)out_he;

  hipMemsetAsync(sc + SC_CNT, 0, N_NODES * sizeof(int), stream);
  hist_kernel<<<(N_EDGES + 255) / 256, 256, 0, stream>>>(ei, sc);
  scan1_kernel<<<NBLK_SCAN, 256, 0, stream>>>(sc);
  scan2_kernel<<<1, 256, 0, stream>>>(sc);
  scan3_kernel<<<NBLK_SCAN, 256, 0, stream>>>(sc);
  fill_kernel<<<(N_EDGES + 255) / 256, 256, 0, stream>>>(ei, sc);
  gather_kernel<<<N_NODES / 8, 192, 0, stream>>>(edge_attr, sc, agg);

  copy_ei_kernel<<<(2 * N_EDGES + 255) / 256, 256, 0, stream>>>(ei, out_ei);
  node_mlp_kernel<<<(N_NODES + BM - 1) / BM, 256, 0, stream>>>(
      x, agg, Wn1, bn1, Wn2, bn2, out_hv);
  edge_mlp_kernel<<<N_EDGES / BM, 256, 0, stream>>>(x, ei, edge_attr, We1, be1,
                                                    We2, be2, out_he);
}